// Round 1
// baseline (23164.825 us; speedup 1.0000x reference)
//
#include <hip/hip_runtime.h>
#include <stdint.h>

#define T_FRAMES 1500
#define B_BATCH  32
#define E_DIM    512
#define H_DIM    512
#define NCLS     31
#define L_STEPS  101
#define EOS_TOK  30

typedef unsigned short ushort_t;
typedef ushort_t ushort8_t __attribute__((ext_vector_type(8)));

__device__ __forceinline__ float bf2f(ushort_t u) {
    union { unsigned int i; float f; } v; v.i = ((unsigned int)u) << 16; return v.f;
}
__device__ __forceinline__ ushort_t f2bf(float f) {
    union { float f; unsigned int i; } v; v.f = f;
    unsigned int r = v.i + 0x7FFFu + ((v.i >> 16) & 1u);
    return (ushort_t)(r >> 16);
}
__device__ __forceinline__ float wave_sum(float v) {
    #pragma unroll
    for (int o = 32; o > 0; o >>= 1) v += __shfl_xor(v, o, 64);
    return v;
}

// ---------------- init: texts2, h-state, loss acc ----------------
__global__ __launch_bounds__(256) void init_kernel(
    const int* __restrict__ texts, const int* __restrict__ text_lens,
    const float* __restrict__ h0p,
    int* __restrict__ texts2, float* __restrict__ h0buf, float* __restrict__ h1buf,
    float* __restrict__ acc)
{
    int idx = blockIdx.x * 256 + threadIdx.x;
    if (idx < 2) acc[idx] = 0.f;
    if (idx < B_BATCH * L_STEPS) {
        int b = idx / L_STEPS, j = idx % L_STEPS;
        int v = (j < 100) ? texts[b * 100 + j] : 0;
        if (j == text_lens[b]) v = EOS_TOK;
        texts2[idx] = v;
    }
    for (int i = idx; i < B_BATCH * H_DIM; i += gridDim.x * 256) {
        h0buf[i] = h0p[i & (H_DIM - 1)];
        h1buf[i] = h0p[H_DIM + (i & (H_DIM - 1))];
    }
}

// ---------------- enc_contrib GEMM: [48000x512] = encoded[48000x512] * W_enc^T, + b_enc, -> bf16
#define GTM 128
#define GTN 128
#define GTK 32
#define GLDA (GTM + 4)

__global__ __launch_bounds__(256) void enc_gemm_kernel(
    const float* __restrict__ A, const float* __restrict__ W,
    const float* __restrict__ bias, ushort_t* __restrict__ C)
{
    __shared__ float As[GTK][GLDA];
    __shared__ float Bs[GTK][GLDA];
    const int m0 = blockIdx.y * GTM;
    const int n0 = blockIdx.x * GTN;
    const int tid = threadIdx.x;
    const int tx = tid & 15, ty = tid >> 4;
    const int lr = tid >> 3;           // 0..31
    const int lc = (tid & 7) << 2;     // 0..28 step 4
    float acc[8][8] = {};
    for (int k0 = 0; k0 < E_DIM; k0 += GTK) {
        #pragma unroll
        for (int p = 0; p < 4; ++p) {
            float4 a = *(const float4*)(A + (size_t)(m0 + lr + 32 * p) * E_DIM + k0 + lc);
            As[lc + 0][lr + 32 * p] = a.x; As[lc + 1][lr + 32 * p] = a.y;
            As[lc + 2][lr + 32 * p] = a.z; As[lc + 3][lr + 32 * p] = a.w;
            float4 b = *(const float4*)(W + (size_t)(n0 + lr + 32 * p) * E_DIM + k0 + lc);
            Bs[lc + 0][lr + 32 * p] = b.x; Bs[lc + 1][lr + 32 * p] = b.y;
            Bs[lc + 2][lr + 32 * p] = b.z; Bs[lc + 3][lr + 32 * p] = b.w;
        }
        __syncthreads();
        #pragma unroll
        for (int k = 0; k < GTK; ++k) {
            float av[8], bv[8];
            *(float4*)&av[0] = *(const float4*)&As[k][ty * 8];
            *(float4*)&av[4] = *(const float4*)&As[k][ty * 8 + 4];
            *(float4*)&bv[0] = *(const float4*)&Bs[k][tx * 8];
            *(float4*)&bv[4] = *(const float4*)&Bs[k][tx * 8 + 4];
            #pragma unroll
            for (int i = 0; i < 8; ++i)
                #pragma unroll
                for (int j = 0; j < 8; ++j)
                    acc[i][j] = fmaf(av[i], bv[j], acc[i][j]);
        }
        __syncthreads();
    }
    const float* bp = bias + n0 + tx * 8;
    #pragma unroll
    for (int i = 0; i < 8; ++i) {
        int m = m0 + ty * 8 + i;
        ushort8_t o;
        #pragma unroll
        for (int j = 0; j < 8; ++j) o[j] = f2bf(acc[i][j] + bp[j]);
        *(ushort8_t*)(C + (size_t)m * H_DIM + n0 + tx * 8) = o;
    }
}

// ---------------- rec = h0 @ W_rec^T : wave per output ----------------
__global__ __launch_bounds__(256) void rec_kernel(
    const float* __restrict__ h0cur, const float* __restrict__ W_rec,
    float* __restrict__ rec)
{
    int wid = threadIdx.x >> 6, lane = threadIdx.x & 63;
    int o = blockIdx.x * 4 + wid;      // o = h*32 + b  (same-h waves adjacent -> L2 row reuse)
    int b = o & 31, h = o >> 5;
    const float* hp = h0cur + b * H_DIM;
    const float* wp = W_rec + (size_t)h * H_DIM;
    int k = lane * 8;
    float4 h0v = *(const float4*)(hp + k);
    float4 h1v = *(const float4*)(hp + k + 4);
    float4 w0v = *(const float4*)(wp + k);
    float4 w1v = *(const float4*)(wp + k + 4);
    float s = h0v.x * w0v.x + h0v.y * w0v.y + h0v.z * w0v.z + h0v.w * w0v.w
            + h1v.x * w1v.x + h1v.y * w1v.y + h1v.z * w1v.z + h1v.w * w1v.w;
    s = wave_sum(s);
    if (lane == 0) rec[b * H_DIM + h] = s;
}

// ---------------- scores[t][b] = tanh(ec + rec) . w_score + b_score ----------------
__global__ __launch_bounds__(256) void scores_kernel(
    const ushort_t* __restrict__ ec, const float* __restrict__ rec,
    const float* __restrict__ w_score, const float* __restrict__ b_score,
    const int* __restrict__ lens, float* __restrict__ scores)
{
    int wid = threadIdx.x >> 6, lane = threadIdx.x & 63;
    int t = blockIdx.x * 4 + wid;
    int b = blockIdx.y;
    if (t >= lens[b]) return;          // masked positions: att==0 exactly, skip
    int k = lane * 8;
    ushort8_t e8 = *(const ushort8_t*)(ec + ((size_t)t * B_BATCH + b) * H_DIM + k);
    const float* rp = rec + b * H_DIM + k;
    const float* wp = w_score + k;
    float s = 0.f;
    #pragma unroll
    for (int j = 0; j < 8; ++j) {
        float x = bf2f(e8[j]) + rp[j];
        s = fmaf(tanhf(x), wp[j], s);
    }
    s = wave_sum(s);
    if (lane == 0) scores[t * B_BATCH + b] = s + b_score[0];
}

// ---------------- softmax stats (max, denom) per b; also zero context ----------------
__global__ __launch_bounds__(256) void stats_kernel(
    const float* __restrict__ scores, const int* __restrict__ lens,
    float* __restrict__ stats, float* __restrict__ context)
{
    __shared__ float red[256];
    int b = blockIdx.x, tid = threadIdx.x;
    int len = lens[b];
    float m = -1e30f;
    for (int t = tid; t < len; t += 256) m = fmaxf(m, scores[t * B_BATCH + b]);
    red[tid] = m; __syncthreads();
    for (int s = 128; s > 0; s >>= 1) {
        if (tid < s) red[tid] = fmaxf(red[tid], red[tid + s]);
        __syncthreads();
    }
    m = red[0]; __syncthreads();
    float sum = 0.f;
    for (int t = tid; t < len; t += 256) sum += expf(scores[t * B_BATCH + b] - m);
    red[tid] = sum; __syncthreads();
    for (int s = 128; s > 0; s >>= 1) {
        if (tid < s) red[tid] += red[tid + s];
        __syncthreads();
    }
    if (tid == 0) { stats[b * 2] = m; stats[b * 2 + 1] = red[0]; }
    context[b * E_DIM + tid] = 0.f;
    context[b * E_DIM + tid + 256] = 0.f;
}

// ---------------- context[b][e] = sum_t att[t,b] * encoded[t,b,e] ----------------
#define CT_CHUNKS 16
__global__ __launch_bounds__(256) void context_kernel(
    const float* __restrict__ scores, const float* __restrict__ stats,
    const float* __restrict__ encoded, const int* __restrict__ lens,
    float* __restrict__ context)
{
    int b = blockIdx.y, chunk = blockIdx.x, tid = threadIdx.x;
    int len = lens[b];
    const int per = (T_FRAMES + CT_CHUNKS - 1) / CT_CHUNKS;
    int t0 = chunk * per, t1 = min(t0 + per, len);
    if (t0 >= t1) return;
    float m = stats[b * 2], inv = 1.0f / stats[b * 2 + 1];
    float a0 = 0.f, a1 = 0.f;
    for (int t = t0; t < t1; ++t) {
        float att = expf(scores[t * B_BATCH + b] - m) * inv;
        const float* er = encoded + ((size_t)t * B_BATCH + b) * E_DIM;
        a0 = fmaf(att, er[tid], a0);
        a1 = fmaf(att, er[tid + 256], a1);
    }
    atomicAdd(&context[b * E_DIM + tid], a0);
    atomicAdd(&context[b * E_DIM + tid + 256], a1);
}

// ---------------- GRU layer 0: x = [emb(token), context] ----------------
__global__ __launch_bounds__(256) void gru0_kernel(
    int l, const int* __restrict__ texts2, const float* __restrict__ emb,
    const float* __restrict__ context, const float* __restrict__ h_prev,
    float* __restrict__ h_new,
    const float* __restrict__ W_ih, const float* __restrict__ W_hh,
    const float* __restrict__ b_ih, const float* __restrict__ b_hh)
{
    int wid = threadIdx.x >> 6, lane = threadIdx.x & 63;
    int o = blockIdx.x * 4 + wid;
    int b = o & 31, h = o >> 5;
    int token = (l > 0) ? texts2[b * L_STEPS + (l - 1)] : -1;
    const float* embp = (token >= 0) ? (emb + (size_t)token * H_DIM) : nullptr;
    const float* ctx = context + b * E_DIM;
    const float* hp = h_prev + b * H_DIM;
    const int IN = H_DIM + E_DIM;   // 1024
    const float* wr = W_ih + (size_t)h * IN;
    const float* wz = W_ih + (size_t)(H_DIM + h) * IN;
    const float* wn = W_ih + (size_t)(2 * H_DIM + h) * IN;
    float ir = 0.f, iz = 0.f, in_ = 0.f;
    int k0 = lane * 16;   // lanes 0..31 -> emb half, 32..63 -> context half
    #pragma unroll
    for (int j = 0; j < 16; ++j) {
        int k = k0 + j;
        float xv = (k < H_DIM) ? (embp ? embp[k] : 0.f) : ctx[k - H_DIM];
        ir  = fmaf(xv, wr[k], ir);
        iz  = fmaf(xv, wz[k], iz);
        in_ = fmaf(xv, wn[k], in_);
    }
    const float* vr = W_hh + (size_t)h * H_DIM;
    const float* vz = W_hh + (size_t)(H_DIM + h) * H_DIM;
    const float* vn = W_hh + (size_t)(2 * H_DIM + h) * H_DIM;
    float hr = 0.f, hz = 0.f, hn = 0.f;
    int k1 = lane * 8;
    #pragma unroll
    for (int j = 0; j < 8; ++j) {
        int k = k1 + j;
        float hv = hp[k];
        hr = fmaf(hv, vr[k], hr);
        hz = fmaf(hv, vz[k], hz);
        hn = fmaf(hv, vn[k], hn);
    }
    ir = wave_sum(ir); iz = wave_sum(iz); in_ = wave_sum(in_);
    hr = wave_sum(hr); hz = wave_sum(hz); hn = wave_sum(hn);
    if (lane == 0) {
        float r = 1.f / (1.f + expf(-(ir + b_ih[h] + hr + b_hh[h])));
        float z = 1.f / (1.f + expf(-(iz + b_ih[H_DIM + h] + hz + b_hh[H_DIM + h])));
        float n = tanhf(in_ + b_ih[2 * H_DIM + h] + r * (hn + b_hh[2 * H_DIM + h]));
        h_new[b * H_DIM + h] = (1.f - z) * n + z * hp[h];
    }
}

// ---------------- GRU layer 1: x = h0_new; writes h1_new and outputs[l] ----------------
__global__ __launch_bounds__(256) void gru1_kernel(
    int l, const float* __restrict__ x, const float* __restrict__ h_prev,
    float* __restrict__ h_new, float* __restrict__ outputs,
    const float* __restrict__ W_ih, const float* __restrict__ W_hh,
    const float* __restrict__ b_ih, const float* __restrict__ b_hh)
{
    int wid = threadIdx.x >> 6, lane = threadIdx.x & 63;
    int o = blockIdx.x * 4 + wid;
    int b = o & 31, h = o >> 5;
    const float* xp = x + b * H_DIM;
    const float* hp = h_prev + b * H_DIM;
    const float* wr = W_ih + (size_t)h * H_DIM;
    const float* wz = W_ih + (size_t)(H_DIM + h) * H_DIM;
    const float* wn = W_ih + (size_t)(2 * H_DIM + h) * H_DIM;
    const float* vr = W_hh + (size_t)h * H_DIM;
    const float* vz = W_hh + (size_t)(H_DIM + h) * H_DIM;
    const float* vn = W_hh + (size_t)(2 * H_DIM + h) * H_DIM;
    float ir = 0.f, iz = 0.f, in_ = 0.f, hr = 0.f, hz = 0.f, hn = 0.f;
    int k0 = lane * 8;
    #pragma unroll
    for (int j = 0; j < 8; ++j) {
        int k = k0 + j;
        float xv = xp[k], hv = hp[k];
        ir  = fmaf(xv, wr[k], ir);
        iz  = fmaf(xv, wz[k], iz);
        in_ = fmaf(xv, wn[k], in_);
        hr  = fmaf(hv, vr[k], hr);
        hz  = fmaf(hv, vz[k], hz);
        hn  = fmaf(hv, vn[k], hn);
    }
    ir = wave_sum(ir); iz = wave_sum(iz); in_ = wave_sum(in_);
    hr = wave_sum(hr); hz = wave_sum(hz); hn = wave_sum(hn);
    if (lane == 0) {
        float r = 1.f / (1.f + expf(-(ir + b_ih[h] + hr + b_hh[h])));
        float z = 1.f / (1.f + expf(-(iz + b_ih[H_DIM + h] + hz + b_hh[H_DIM + h])));
        float n = tanhf(in_ + b_ih[2 * H_DIM + h] + r * (hn + b_hh[2 * H_DIM + h]));
        float out = (1.f - z) * n + z * hp[h];
        h_new[b * H_DIM + h] = out;
        outputs[((size_t)l * B_BATCH + b) * H_DIM + h] = out;
    }
}

// ---------------- loss: logits -> log_softmax -> masked NLL mean ----------------
__global__ __launch_bounds__(256) void loss_kernel(
    const float* __restrict__ outputs, const int* __restrict__ texts2,
    const float* __restrict__ W_out, const float* __restrict__ b_out,
    float* __restrict__ acc)
{
    int wid = threadIdx.x >> 6, lane = threadIdx.x & 63;
    int gw = blockIdx.x * 4 + wid;
    int nw = gridDim.x * 4;
    float lsum = 0.f, lcnt = 0.f;
    for (int r = gw; r < B_BATCH * L_STEPS; r += nw) {
        int b = r / L_STEPS, l = r % L_STEPS;
        int label = texts2[r];          // texts2 is [b][l] flat == r
        const float* orow = outputs + ((size_t)l * B_BATCH + b) * H_DIM;
        int k = lane * 8;
        float o8[8];
        *(float4*)&o8[0] = *(const float4*)(orow + k);
        *(float4*)&o8[4] = *(const float4*)(orow + k + 4);
        float m = -1e30f, se = 0.f, ll = 0.f;
        for (int c = 0; c < NCLS; ++c) {
            const float* wrow = W_out + (size_t)c * H_DIM + k;
            float p = 0.f;
            #pragma unroll
            for (int j = 0; j < 8; ++j) p = fmaf(o8[j], wrow[j], p);
            float logit = wave_sum(p) + b_out[c];
            if (c == label) ll = logit;
            if (logit > m) { se = se * expf(m - logit) + 1.f; m = logit; }
            else           { se += expf(logit - m); }
        }
        float lse = m + logf(se);
        if (label != 0) { lsum += lse - ll; lcnt += 1.f; }
    }
    if (lane == 0) { atomicAdd(&acc[0], lsum); atomicAdd(&acc[1], lcnt); }
}

__global__ void finalize_kernel(const float* __restrict__ acc, float* __restrict__ out) {
    out[0] = acc[0] / fmaxf(acc[1], 1.0f);
}

// ---------------- launch ----------------
extern "C" void kernel_launch(void* const* d_in, const int* in_sizes, int n_in,
                              void* d_out, int out_size, void* d_ws, size_t ws_size,
                              hipStream_t stream) {
    (void)in_sizes; (void)n_in; (void)out_size; (void)ws_size;
    const float* encoded      = (const float*)d_in[0];
    const int*   encoded_lens = (const int*)d_in[1];
    const int*   texts        = (const int*)d_in[2];
    const int*   text_lens    = (const int*)d_in[3];
    const float* W_enc        = (const float*)d_in[4];
    const float* b_enc        = (const float*)d_in[5];
    const float* W_rec        = (const float*)d_in[6];
    const float* w_score      = (const float*)d_in[7];
    const float* b_score      = (const float*)d_in[8];
    const float* emb          = (const float*)d_in[9];
    const float* W_ih0        = (const float*)d_in[10];
    const float* W_hh0        = (const float*)d_in[11];
    const float* b_ih0        = (const float*)d_in[12];
    const float* b_hh0        = (const float*)d_in[13];
    const float* W_ih1        = (const float*)d_in[14];
    const float* W_hh1        = (const float*)d_in[15];
    const float* b_ih1        = (const float*)d_in[16];
    const float* b_hh1        = (const float*)d_in[17];
    const float* W_out        = (const float*)d_in[18];
    const float* b_out        = (const float*)d_in[19];
    const float* h0p          = (const float*)d_in[20];

    char* ws = (char*)d_ws;
    size_t off = 0;
    ushort_t* ec = (ushort_t*)(ws + off); off += (size_t)T_FRAMES * B_BATCH * H_DIM * 2;   // 49.15 MB
    float* scores  = (float*)(ws + off); off += (size_t)T_FRAMES * B_BATCH * 4;
    float* stats   = (float*)(ws + off); off += 256;
    float* context = (float*)(ws + off); off += (size_t)B_BATCH * E_DIM * 4;
    float* rec     = (float*)(ws + off); off += (size_t)B_BATCH * H_DIM * 4;
    float* hb[4];
    for (int i = 0; i < 4; ++i) { hb[i] = (float*)(ws + off); off += (size_t)B_BATCH * H_DIM * 4; }
    float* outputs = (float*)(ws + off); off += (size_t)L_STEPS * B_BATCH * H_DIM * 4;
    int*   texts2  = (int*)(ws + off); off += (size_t)B_BATCH * L_STEPS * 4;
    float* acc     = (float*)(ws + off); off += 256;

    init_kernel<<<64, 256, 0, stream>>>(texts, text_lens, h0p, texts2, hb[0], hb[2], acc);
    enc_gemm_kernel<<<dim3(E_DIM / GTN, (T_FRAMES * B_BATCH) / GTM), 256, 0, stream>>>(
        encoded, W_enc, b_enc, ec);

    for (int l = 0; l < L_STEPS; ++l) {
        int cur = l & 1, nxt = cur ^ 1;
        rec_kernel<<<(B_BATCH * H_DIM) / 4, 256, 0, stream>>>(hb[cur], W_rec, rec);
        scores_kernel<<<dim3((T_FRAMES + 3) / 4, B_BATCH), 256, 0, stream>>>(
            ec, rec, w_score, b_score, encoded_lens, scores);
        stats_kernel<<<B_BATCH, 256, 0, stream>>>(scores, encoded_lens, stats, context);
        context_kernel<<<dim3(CT_CHUNKS, B_BATCH), 256, 0, stream>>>(
            scores, stats, encoded, encoded_lens, context);
        gru0_kernel<<<(B_BATCH * H_DIM) / 4, 256, 0, stream>>>(
            l, texts2, emb, context, hb[cur], hb[nxt], W_ih0, W_hh0, b_ih0, b_hh0);
        gru1_kernel<<<(B_BATCH * H_DIM) / 4, 256, 0, stream>>>(
            l, hb[nxt], hb[2 + cur], hb[2 + nxt], outputs, W_ih1, W_hh1, b_ih1, b_hh1);
    }

    loss_kernel<<<64, 256, 0, stream>>>(outputs, texts2, W_out, b_out, acc);
    finalize_kernel<<<1, 1, 0, stream>>>(acc, (float*)d_out);
}

// Round 2
// 16303.758 us; speedup vs baseline: 1.4208x; 1.4208x over previous
//
#include <hip/hip_runtime.h>
#include <hip/hip_cooperative_groups.h>
#include <stdint.h>

namespace cg = cooperative_groups;

#define T_FRAMES 1500
#define B_BATCH  32
#define E_DIM    512
#define H_DIM    512
#define NCLS     31
#define L_STEPS  101
#define EOS_TOK  30
#define NBLK     256
#define NTHR     512
#define ROWS_A   24          // 64 chunks * 24 rows = 1536 >= 1500

typedef unsigned short ushort_t;
typedef ushort_t ushort8_t __attribute__((ext_vector_type(8)));

__device__ __forceinline__ float bf2f(ushort_t u) {
    union { unsigned int i; float f; } v; v.i = ((unsigned int)u) << 16; return v.f;
}
__device__ __forceinline__ ushort_t f2bf(float f) {
    union { float f; unsigned int i; } v; v.f = f;
    unsigned int r = v.i + 0x7FFFu + ((v.i >> 16) & 1u);
    return (ushort_t)(r >> 16);
}
__device__ __forceinline__ float wave_sum(float v) {
    #pragma unroll
    for (int o = 32; o > 0; o >>= 1) v += __shfl_xor(v, o, 64);
    return v;
}
template<int N>
__device__ __forceinline__ void wave_sum_n(float* v) {
    #pragma unroll
    for (int o = 32; o > 0; o >>= 1) {
        #pragma unroll
        for (int i = 0; i < N; ++i) v[i] += __shfl_xor(v[i], o, 64);
    }
}

// ---------------- one-time f32 -> bf16 convert ----------------
__global__ __launch_bounds__(256) void cvt_kernel(const float* __restrict__ in,
                                                  ushort_t* __restrict__ out, int n) {
    int i = (blockIdx.x * 256 + threadIdx.x) * 8;
    if (i >= n) return;
    float4 a = *(const float4*)(in + i);
    float4 b = *(const float4*)(in + i + 4);
    ushort8_t o;
    o[0] = f2bf(a.x); o[1] = f2bf(a.y); o[2] = f2bf(a.z); o[3] = f2bf(a.w);
    o[4] = f2bf(b.x); o[5] = f2bf(b.y); o[6] = f2bf(b.z); o[7] = f2bf(b.w);
    *(ushort8_t*)(out + i) = o;
}

// ---------------- enc_contrib GEMM (f32 in, bf16 out) ----------------
#define GTM 128
#define GTN 128
#define GTK 32
#define GLDA (GTM + 4)

__global__ __launch_bounds__(256) void enc_gemm_kernel(
    const float* __restrict__ A, const float* __restrict__ W,
    const float* __restrict__ bias, ushort_t* __restrict__ C)
{
    __shared__ float As[GTK][GLDA];
    __shared__ float Bs[GTK][GLDA];
    const int m0 = blockIdx.y * GTM;
    const int n0 = blockIdx.x * GTN;
    const int tid = threadIdx.x;
    const int tx = tid & 15, ty = tid >> 4;
    const int lr = tid >> 3;
    const int lc = (tid & 7) << 2;
    float acc[8][8] = {};
    for (int k0 = 0; k0 < E_DIM; k0 += GTK) {
        #pragma unroll
        for (int p = 0; p < 4; ++p) {
            float4 a = *(const float4*)(A + (size_t)(m0 + lr + 32 * p) * E_DIM + k0 + lc);
            As[lc + 0][lr + 32 * p] = a.x; As[lc + 1][lr + 32 * p] = a.y;
            As[lc + 2][lr + 32 * p] = a.z; As[lc + 3][lr + 32 * p] = a.w;
            float4 b = *(const float4*)(W + (size_t)(n0 + lr + 32 * p) * E_DIM + k0 + lc);
            Bs[lc + 0][lr + 32 * p] = b.x; Bs[lc + 1][lr + 32 * p] = b.y;
            Bs[lc + 2][lr + 32 * p] = b.z; Bs[lc + 3][lr + 32 * p] = b.w;
        }
        __syncthreads();
        #pragma unroll
        for (int k = 0; k < GTK; ++k) {
            float av[8], bv[8];
            *(float4*)&av[0] = *(const float4*)&As[k][ty * 8];
            *(float4*)&av[4] = *(const float4*)&As[k][ty * 8 + 4];
            *(float4*)&bv[0] = *(const float4*)&Bs[k][tx * 8];
            *(float4*)&bv[4] = *(const float4*)&Bs[k][tx * 8 + 4];
            #pragma unroll
            for (int i = 0; i < 8; ++i)
                #pragma unroll
                for (int j = 0; j < 8; ++j)
                    acc[i][j] = fmaf(av[i], bv[j], acc[i][j]);
        }
        __syncthreads();
    }
    const float* bp = bias + n0 + tx * 8;
    #pragma unroll
    for (int i = 0; i < 8; ++i) {
        int m = m0 + ty * 8 + i;
        ushort8_t o;
        #pragma unroll
        for (int j = 0; j < 8; ++j) o[j] = f2bf(acc[i][j] + bp[j]);
        *(ushort8_t*)(C + (size_t)m * H_DIM + n0 + tx * 8) = o;
    }
}

// ---------------- persistent cooperative decoder ----------------
struct Params {
    const float* encoded; const int* lens; const float* emb; const float* h0p;
    const int* texts; const int* text_lens;
    const float* w_score; const float* b_score;
    const float* b_ih0; const float* b_hh0; const float* b_ih1; const float* b_hh1;
    const ushort_t* ec; const ushort_t* encB;
    const ushort_t* Wrec; const ushort_t* Wih0; const ushort_t* Whh0;
    const ushort_t* Wih1; const ushort_t* Whh1;
    float* rec; float* context; float* denom;
    float* h0a; float* h0b; float* h1a; float* h1b;
    float* outputs; int* texts2; float* acc;
    int useEncB;
};

__global__ __launch_bounds__(NTHR, 1) void decoder_kernel(Params p) {
    cg::grid_group grid = cg::this_grid();
    const int tid = threadIdx.x;
    const int bid = blockIdx.x;
    const int lane = tid & 63;
    const int wsub = tid >> 6;            // 0..7
    const int gid = bid * NTHR + tid;
    const int W = bid * 8 + wsub;         // 0..2047
    __shared__ float sctx[8][E_DIM];

    // ---- init ----
    if (gid < B_BATCH * L_STEPS) {
        int b = gid / L_STEPS, j = gid % L_STEPS;
        int v = (j < 100) ? p.texts[b * 100 + j] : 0;
        if (j == p.text_lens[b]) v = EOS_TOK;
        p.texts2[gid] = v;
    }
    if (gid < B_BATCH * H_DIM) {
        p.h0a[gid] = p.h0p[gid & (H_DIM - 1)];
        p.h1a[gid] = p.h0p[H_DIM + (gid & (H_DIM - 1))];
        p.context[gid] = 0.f;
    }
    if (gid < B_BATCH) p.denom[gid] = 0.f;
    if (gid < 2) p.acc[gid] = 0.f;
    grid.sync();

    // ---- initial rec from h0a ----
    {
        int b = W >> 6, hbase = (W & 63) * 8;
        const float* x = p.h0a + b * H_DIM + lane * 8;
        float x8[8];
        *(float4*)&x8[0] = *(const float4*)(x);
        *(float4*)&x8[4] = *(const float4*)(x + 4);
        #pragma unroll
        for (int i = 0; i < 8; ++i) {
            int h = hbase + i;
            ushort8_t w8 = *(const ushort8_t*)(p.Wrec + (size_t)h * H_DIM + lane * 8);
            float s = 0.f;
            #pragma unroll
            for (int j = 0; j < 8; ++j) s = fmaf(x8[j], bf2f(w8[j]), s);
            s = wave_sum(s);
            if (lane == 0) p.rec[b * H_DIM + h] = s;
        }
    }
    grid.sync();

    for (int l = 0; l < L_STEPS; ++l) {
        const float* h0cur = (l & 1) ? p.h0b : p.h0a;
        float*       h0nxt = (l & 1) ? p.h0a : p.h0b;
        const float* h1cur = (l & 1) ? p.h1b : p.h1a;
        float*       h1nxt = (l & 1) ? p.h1a : p.h1b;

        // ---- phase A: scores + exp + context partials + denom ----
        {
            int b = bid & 31;
            int chunk = (bid >> 5) * 8 + wsub;      // 0..63
            int len = p.lens[b];
            int t0 = chunk * ROWS_A;
            int t1 = min(t0 + ROWS_A, len);
            float rec8[8], w8[8];
            const float* rp = p.rec + b * H_DIM + lane * 8;
            *(float4*)&rec8[0] = *(const float4*)(rp);
            *(float4*)&rec8[4] = *(const float4*)(rp + 4);
            const float* wp = p.w_score + lane * 8;
            *(float4*)&w8[0] = *(const float4*)(wp);
            *(float4*)&w8[4] = *(const float4*)(wp + 4);
            float bsc = p.b_score[0];
            float acc8[8] = {0.f,0.f,0.f,0.f,0.f,0.f,0.f,0.f};
            float dsum = 0.f;
            if (p.useEncB) {
                for (int t = t0; t < t1; ++t) {
                    size_t row = ((size_t)t * B_BATCH + b) * H_DIM + lane * 8;
                    ushort8_t e8 = *(const ushort8_t*)(p.ec + row);
                    float s = 0.f;
                    #pragma unroll
                    for (int j = 0; j < 8; ++j)
                        s = fmaf(tanhf(bf2f(e8[j]) + rec8[j]), w8[j], s);
                    s = wave_sum(s) + bsc;
                    float pv = expf(s);
                    dsum += pv;
                    ushort8_t v8 = *(const ushort8_t*)(p.encB + row);
                    #pragma unroll
                    for (int j = 0; j < 8; ++j)
                        acc8[j] = fmaf(pv, bf2f(v8[j]), acc8[j]);
                }
            } else {
                for (int t = t0; t < t1; ++t) {
                    size_t row = ((size_t)t * B_BATCH + b) * H_DIM + lane * 8;
                    ushort8_t e8 = *(const ushort8_t*)(p.ec + row);
                    float s = 0.f;
                    #pragma unroll
                    for (int j = 0; j < 8; ++j)
                        s = fmaf(tanhf(bf2f(e8[j]) + rec8[j]), w8[j], s);
                    s = wave_sum(s) + bsc;
                    float pv = expf(s);
                    dsum += pv;
                    float v8[8];
                    const float* vp = p.encoded + row;
                    *(float4*)&v8[0] = *(const float4*)(vp);
                    *(float4*)&v8[4] = *(const float4*)(vp + 4);
                    #pragma unroll
                    for (int j = 0; j < 8; ++j)
                        acc8[j] = fmaf(pv, v8[j], acc8[j]);
                }
            }
            *(float4*)&sctx[wsub][lane * 8]     = *(float4*)&acc8[0];
            *(float4*)&sctx[wsub][lane * 8 + 4] = *(float4*)&acc8[4];
            __syncthreads();
            float csum = 0.f;
            #pragma unroll
            for (int w = 0; w < 8; ++w) csum += sctx[w][tid];
            if (csum != 0.f) atomicAdd(&p.context[b * E_DIM + tid], csum);
            if (lane == 0 && dsum != 0.f) atomicAdd(&p.denom[b], dsum);
        }
        grid.sync();

        // ---- phase B: GRU layer 0 ----
        {
            int b = W >> 6, hbase = (W & 63) * 8;
            int token = (l > 0) ? p.texts2[b * L_STEPS + l - 1] : -1;
            float inv = 1.0f / p.denom[b];
            float x16[16];
            int k0 = lane * 16;
            if (k0 < H_DIM) {
                if (token >= 0) {
                    const float* ep = p.emb + (size_t)token * H_DIM + k0;
                    #pragma unroll
                    for (int q = 0; q < 4; ++q)
                        *(float4*)&x16[q * 4] = *(const float4*)(ep + q * 4);
                } else {
                    #pragma unroll
                    for (int j = 0; j < 16; ++j) x16[j] = 0.f;
                }
            } else {
                const float* cp = p.context + b * E_DIM + (k0 - H_DIM);
                #pragma unroll
                for (int q = 0; q < 4; ++q) {
                    float4 c = *(const float4*)(cp + q * 4);
                    x16[q * 4 + 0] = c.x * inv; x16[q * 4 + 1] = c.y * inv;
                    x16[q * 4 + 2] = c.z * inv; x16[q * 4 + 3] = c.w * inv;
                }
            }
            float h8[8];
            const float* hp = h0cur + b * H_DIM + lane * 8;
            *(float4*)&h8[0] = *(const float4*)(hp);
            *(float4*)&h8[4] = *(const float4*)(hp + 4);
            const int IN = H_DIM + E_DIM;
            for (int i = 0; i < 8; ++i) {
                int h = hbase + i;
                float v[6] = {0.f,0.f,0.f,0.f,0.f,0.f};
                #pragma unroll
                for (int g = 0; g < 3; ++g) {
                    const ushort_t* r = p.Wih0 + (size_t)(g * H_DIM + h) * IN + k0;
                    ushort8_t a = *(const ushort8_t*)(r);
                    ushort8_t c = *(const ushort8_t*)(r + 8);
                    #pragma unroll
                    for (int j = 0; j < 8; ++j) {
                        v[g] = fmaf(x16[j], bf2f(a[j]), v[g]);
                        v[g] = fmaf(x16[8 + j], bf2f(c[j]), v[g]);
                    }
                }
                #pragma unroll
                for (int g = 0; g < 3; ++g) {
                    const ushort_t* r = p.Whh0 + (size_t)(g * H_DIM + h) * H_DIM + lane * 8;
                    ushort8_t a = *(const ushort8_t*)(r);
                    #pragma unroll
                    for (int j = 0; j < 8; ++j)
                        v[3 + g] = fmaf(h8[j], bf2f(a[j]), v[3 + g]);
                }
                wave_sum_n<6>(v);
                if (lane == 0) {
                    float r = 1.f / (1.f + expf(-(v[0] + p.b_ih0[h] + v[3] + p.b_hh0[h])));
                    float z = 1.f / (1.f + expf(-(v[1] + p.b_ih0[H_DIM + h] + v[4] + p.b_hh0[H_DIM + h])));
                    float n = tanhf(v[2] + p.b_ih0[2 * H_DIM + h] + r * (v[5] + p.b_hh0[2 * H_DIM + h]));
                    float hv = h0cur[b * H_DIM + h];
                    h0nxt[b * H_DIM + h] = (1.f - z) * n + z * hv;
                }
            }
        }
        grid.sync();

        // ---- phase C: GRU layer 1 + next rec + zero ctx/denom ----
        {
            if (gid < B_BATCH * E_DIM) p.context[gid] = 0.f;
            if (gid < B_BATCH) p.denom[gid] = 0.f;
            int b = W >> 6, hbase = (W & 63) * 8;
            float x8[8], g8[8];
            const float* xp = h0nxt + b * H_DIM + lane * 8;
            *(float4*)&x8[0] = *(const float4*)(xp);
            *(float4*)&x8[4] = *(const float4*)(xp + 4);
            const float* gp = h1cur + b * H_DIM + lane * 8;
            *(float4*)&g8[0] = *(const float4*)(gp);
            *(float4*)&g8[4] = *(const float4*)(gp + 4);
            for (int i = 0; i < 8; ++i) {
                int h = hbase + i;
                float v[7] = {0.f,0.f,0.f,0.f,0.f,0.f,0.f};
                #pragma unroll
                for (int g = 0; g < 3; ++g) {
                    const ushort_t* r1 = p.Wih1 + (size_t)(g * H_DIM + h) * H_DIM + lane * 8;
                    ushort8_t a = *(const ushort8_t*)(r1);
                    const ushort_t* r2 = p.Whh1 + (size_t)(g * H_DIM + h) * H_DIM + lane * 8;
                    ushort8_t c = *(const ushort8_t*)(r2);
                    #pragma unroll
                    for (int j = 0; j < 8; ++j) {
                        v[g]     = fmaf(x8[j], bf2f(a[j]), v[g]);
                        v[3 + g] = fmaf(g8[j], bf2f(c[j]), v[3 + g]);
                    }
                }
                {
                    const ushort_t* r = p.Wrec + (size_t)h * H_DIM + lane * 8;
                    ushort8_t a = *(const ushort8_t*)(r);
                    #pragma unroll
                    for (int j = 0; j < 8; ++j)
                        v[6] = fmaf(x8[j], bf2f(a[j]), v[6]);
                }
                wave_sum_n<7>(v);
                if (lane == 0) {
                    float r = 1.f / (1.f + expf(-(v[0] + p.b_ih1[h] + v[3] + p.b_hh1[h])));
                    float z = 1.f / (1.f + expf(-(v[1] + p.b_ih1[H_DIM + h] + v[4] + p.b_hh1[H_DIM + h])));
                    float n = tanhf(v[2] + p.b_ih1[2 * H_DIM + h] + r * (v[5] + p.b_hh1[2 * H_DIM + h]));
                    float hv = h1cur[b * H_DIM + h];
                    float out = (1.f - z) * n + z * hv;
                    h1nxt[b * H_DIM + h] = out;
                    p.outputs[((size_t)l * B_BATCH + b) * H_DIM + h] = out;
                    p.rec[b * H_DIM + h] = v[6];
                }
            }
        }
        grid.sync();
    }
}

// ---------------- loss ----------------
__global__ __launch_bounds__(256) void loss_kernel(
    const float* __restrict__ outputs, const int* __restrict__ texts2,
    const float* __restrict__ W_out, const float* __restrict__ b_out,
    float* __restrict__ acc)
{
    int wid = threadIdx.x >> 6, lane = threadIdx.x & 63;
    int gw = blockIdx.x * 4 + wid;
    int nw = gridDim.x * 4;
    float lsum = 0.f, lcnt = 0.f;
    for (int r = gw; r < B_BATCH * L_STEPS; r += nw) {
        int b = r / L_STEPS, l = r % L_STEPS;
        int label = texts2[r];
        const float* orow = outputs + ((size_t)l * B_BATCH + b) * H_DIM;
        int k = lane * 8;
        float o8[8];
        *(float4*)&o8[0] = *(const float4*)(orow + k);
        *(float4*)&o8[4] = *(const float4*)(orow + k + 4);
        float m = -1e30f, se = 0.f, ll = 0.f;
        for (int c = 0; c < NCLS; ++c) {
            const float* wrow = W_out + (size_t)c * H_DIM + k;
            float p = 0.f;
            #pragma unroll
            for (int j = 0; j < 8; ++j) p = fmaf(o8[j], wrow[j], p);
            float logit = wave_sum(p) + b_out[c];
            if (c == label) ll = logit;
            if (logit > m) { se = se * expf(m - logit) + 1.f; m = logit; }
            else           { se += expf(logit - m); }
        }
        float lse = m + logf(se);
        if (label != 0) { lsum += lse - ll; lcnt += 1.f; }
    }
    if (lane == 0) { atomicAdd(&acc[0], lsum); atomicAdd(&acc[1], lcnt); }
}

__global__ void finalize_kernel(const float* __restrict__ acc, float* __restrict__ out) {
    out[0] = acc[0] / fmaxf(acc[1], 1.0f);
}

// ---------------- launch ----------------
static inline size_t align256(size_t x) { return (x + 255) & ~(size_t)255; }

extern "C" void kernel_launch(void* const* d_in, const int* in_sizes, int n_in,
                              void* d_out, int out_size, void* d_ws, size_t ws_size,
                              hipStream_t stream) {
    (void)in_sizes; (void)n_in; (void)out_size;
    const float* encoded      = (const float*)d_in[0];
    const int*   encoded_lens = (const int*)d_in[1];
    const int*   texts        = (const int*)d_in[2];
    const int*   text_lens    = (const int*)d_in[3];
    const float* W_enc        = (const float*)d_in[4];
    const float* b_enc        = (const float*)d_in[5];
    const float* W_rec        = (const float*)d_in[6];
    const float* w_score      = (const float*)d_in[7];
    const float* b_score      = (const float*)d_in[8];
    const float* emb          = (const float*)d_in[9];
    const float* W_ih0        = (const float*)d_in[10];
    const float* W_hh0        = (const float*)d_in[11];
    const float* b_ih0        = (const float*)d_in[12];
    const float* b_hh0        = (const float*)d_in[13];
    const float* W_ih1        = (const float*)d_in[14];
    const float* W_hh1        = (const float*)d_in[15];
    const float* b_ih1        = (const float*)d_in[16];
    const float* b_hh1        = (const float*)d_in[17];
    const float* W_out        = (const float*)d_in[18];
    const float* b_out        = (const float*)d_in[19];
    const float* h0p          = (const float*)d_in[20];

    char* ws = (char*)d_ws;
    size_t off = 0;
    ushort_t* ec     = (ushort_t*)(ws + off); off = align256(off + (size_t)T_FRAMES * B_BATCH * H_DIM * 2);
    ushort_t* Wrecb  = (ushort_t*)(ws + off); off = align256(off + (size_t)H_DIM * H_DIM * 2);
    ushort_t* Wih0b  = (ushort_t*)(ws + off); off = align256(off + (size_t)3 * H_DIM * (H_DIM + E_DIM) * 2);
    ushort_t* Whh0b  = (ushort_t*)(ws + off); off = align256(off + (size_t)3 * H_DIM * H_DIM * 2);
    ushort_t* Wih1b  = (ushort_t*)(ws + off); off = align256(off + (size_t)3 * H_DIM * H_DIM * 2);
    ushort_t* Whh1b  = (ushort_t*)(ws + off); off = align256(off + (size_t)3 * H_DIM * H_DIM * 2);
    float* rec       = (float*)(ws + off); off = align256(off + (size_t)B_BATCH * H_DIM * 4);
    float* context   = (float*)(ws + off); off = align256(off + (size_t)B_BATCH * E_DIM * 4);
    float* denom     = (float*)(ws + off); off = align256(off + (size_t)B_BATCH * 4);
    float* h0a       = (float*)(ws + off); off = align256(off + (size_t)B_BATCH * H_DIM * 4);
    float* h0b       = (float*)(ws + off); off = align256(off + (size_t)B_BATCH * H_DIM * 4);
    float* h1a       = (float*)(ws + off); off = align256(off + (size_t)B_BATCH * H_DIM * 4);
    float* h1b       = (float*)(ws + off); off = align256(off + (size_t)B_BATCH * H_DIM * 4);
    float* outputs   = (float*)(ws + off); off = align256(off + (size_t)L_STEPS * B_BATCH * H_DIM * 4);
    int*   texts2    = (int*)(ws + off); off = align256(off + (size_t)B_BATCH * L_STEPS * 4);
    float* acc       = (float*)(ws + off); off = align256(off + 256);
    size_t encB_off  = off;
    size_t encB_bytes = (size_t)T_FRAMES * B_BATCH * E_DIM * 2;
    int useEncB = (encB_off + encB_bytes <= ws_size) ? 1 : 0;
    ushort_t* encB = (ushort_t*)(ws + encB_off);

    // one-time converts
    cvt_kernel<<<(H_DIM * H_DIM) / (256 * 8), 256, 0, stream>>>(W_rec, Wrecb, H_DIM * H_DIM);
    cvt_kernel<<<(3 * H_DIM * (H_DIM + E_DIM)) / (256 * 8), 256, 0, stream>>>(W_ih0, Wih0b, 3 * H_DIM * (H_DIM + E_DIM));
    cvt_kernel<<<(3 * H_DIM * H_DIM) / (256 * 8), 256, 0, stream>>>(W_hh0, Whh0b, 3 * H_DIM * H_DIM);
    cvt_kernel<<<(3 * H_DIM * H_DIM) / (256 * 8), 256, 0, stream>>>(W_ih1, Wih1b, 3 * H_DIM * H_DIM);
    cvt_kernel<<<(3 * H_DIM * H_DIM) / (256 * 8), 256, 0, stream>>>(W_hh1, Whh1b, 3 * H_DIM * H_DIM);
    if (useEncB) {
        cvt_kernel<<<(T_FRAMES * B_BATCH * E_DIM) / (256 * 8), 256, 0, stream>>>(
            encoded, encB, T_FRAMES * B_BATCH * E_DIM);
    }
    enc_gemm_kernel<<<dim3(H_DIM / GTN, (T_FRAMES * B_BATCH) / GTM), 256, 0, stream>>>(
        encoded, W_enc, b_enc, ec);

    Params prm;
    prm.encoded = encoded; prm.lens = encoded_lens; prm.emb = emb; prm.h0p = h0p;
    prm.texts = texts; prm.text_lens = text_lens;
    prm.w_score = w_score; prm.b_score = b_score;
    prm.b_ih0 = b_ih0; prm.b_hh0 = b_hh0; prm.b_ih1 = b_ih1; prm.b_hh1 = b_hh1;
    prm.ec = ec; prm.encB = encB;
    prm.Wrec = Wrecb; prm.Wih0 = Wih0b; prm.Whh0 = Whh0b; prm.Wih1 = Wih1b; prm.Whh1 = Whh1b;
    prm.rec = rec; prm.context = context; prm.denom = denom;
    prm.h0a = h0a; prm.h0b = h0b; prm.h1a = h1a; prm.h1b = h1b;
    prm.outputs = outputs; prm.texts2 = texts2; prm.acc = acc;
    prm.useEncB = useEncB;

    void* args[] = { &prm };
    hipLaunchCooperativeKernel((const void*)decoder_kernel, dim3(NBLK), dim3(NTHR),
                               args, 0, stream);

    loss_kernel<<<64, 256, 0, stream>>>(outputs, texts2, W_out, b_out, acc);
    finalize_kernel<<<1, 1, 0, stream>>>(acc, (float*)d_out);
}

// Round 3
// 15803.740 us; speedup vs baseline: 1.4658x; 1.0316x over previous
//
#include <hip/hip_runtime.h>
#include <hip/hip_cooperative_groups.h>
#include <stdint.h>

namespace cg = cooperative_groups;

#define T_FRAMES 1500
#define B_BATCH  32
#define E_DIM    512
#define H_DIM    512
#define NCLS     31
#define L_STEPS  101
#define EOS_TOK  30
#define NBLK     256
#define NTHR     1024
#define NWAVE    (NBLK * NTHR / 64)   // 4096
#define CHUNKS_A 128
#define ROWS_A   12                   // 128 * 12 = 1536 >= 1500

typedef unsigned short ushort_t;
typedef ushort_t ushort8_t __attribute__((ext_vector_type(8)));

__device__ __forceinline__ float bf2f(ushort_t u) {
    union { unsigned int i; float f; } v; v.i = ((unsigned int)u) << 16; return v.f;
}
__device__ __forceinline__ ushort_t f2bf(float f) {
    union { float f; unsigned int i; } v; v.f = f;
    unsigned int r = v.i + 0x7FFFu + ((v.i >> 16) & 1u);
    return (ushort_t)(r >> 16);
}
__device__ __forceinline__ float wave_sum(float v) {
    #pragma unroll
    for (int o = 32; o > 0; o >>= 1) v += __shfl_xor(v, o, 64);
    return v;
}
template<int N>
__device__ __forceinline__ void wave_sum_n(float* v) {
    #pragma unroll
    for (int o = 32; o > 0; o >>= 1) {
        #pragma unroll
        for (int i = 0; i < N; ++i) v[i] += __shfl_xor(v[i], o, 64);
    }
}
// fast transcendentals: v_exp_f32 / v_rcp_f32 based
__device__ __forceinline__ float tanh_f(float x) {
    float e = __expf(2.0f * x);
    return 1.0f - 2.0f * __builtin_amdgcn_rcpf(e + 1.0f);
}
__device__ __forceinline__ float sigmoid_f(float x) {
    return __builtin_amdgcn_rcpf(1.0f + __expf(-x));
}

// ---------------- one-time f32 -> bf16 convert ----------------
__global__ __launch_bounds__(256) void cvt_kernel(const float* __restrict__ in,
                                                  ushort_t* __restrict__ out, int n) {
    int i = (blockIdx.x * 256 + threadIdx.x) * 8;
    if (i >= n) return;
    float4 a = *(const float4*)(in + i);
    float4 b = *(const float4*)(in + i + 4);
    ushort8_t o;
    o[0] = f2bf(a.x); o[1] = f2bf(a.y); o[2] = f2bf(a.z); o[3] = f2bf(a.w);
    o[4] = f2bf(b.x); o[5] = f2bf(b.y); o[6] = f2bf(b.z); o[7] = f2bf(b.w);
    *(ushort8_t*)(out + i) = o;
}

// ---------------- enc_contrib GEMM (f32 in, bf16 out) ----------------
#define GTM 128
#define GTN 128
#define GTK 32
#define GLDA (GTM + 4)

__global__ __launch_bounds__(256) void enc_gemm_kernel(
    const float* __restrict__ A, const float* __restrict__ W,
    const float* __restrict__ bias, ushort_t* __restrict__ C)
{
    __shared__ float As[GTK][GLDA];
    __shared__ float Bs[GTK][GLDA];
    const int m0 = blockIdx.y * GTM;
    const int n0 = blockIdx.x * GTN;
    const int tid = threadIdx.x;
    const int tx = tid & 15, ty = tid >> 4;
    const int lr = tid >> 3;
    const int lc = (tid & 7) << 2;
    float acc[8][8] = {};
    for (int k0 = 0; k0 < E_DIM; k0 += GTK) {
        #pragma unroll
        for (int p = 0; p < 4; ++p) {
            float4 a = *(const float4*)(A + (size_t)(m0 + lr + 32 * p) * E_DIM + k0 + lc);
            As[lc + 0][lr + 32 * p] = a.x; As[lc + 1][lr + 32 * p] = a.y;
            As[lc + 2][lr + 32 * p] = a.z; As[lc + 3][lr + 32 * p] = a.w;
            float4 b = *(const float4*)(W + (size_t)(n0 + lr + 32 * p) * E_DIM + k0 + lc);
            Bs[lc + 0][lr + 32 * p] = b.x; Bs[lc + 1][lr + 32 * p] = b.y;
            Bs[lc + 2][lr + 32 * p] = b.z; Bs[lc + 3][lr + 32 * p] = b.w;
        }
        __syncthreads();
        #pragma unroll
        for (int k = 0; k < GTK; ++k) {
            float av[8], bv[8];
            *(float4*)&av[0] = *(const float4*)&As[k][ty * 8];
            *(float4*)&av[4] = *(const float4*)&As[k][ty * 8 + 4];
            *(float4*)&bv[0] = *(const float4*)&Bs[k][tx * 8];
            *(float4*)&bv[4] = *(const float4*)&Bs[k][tx * 8 + 4];
            #pragma unroll
            for (int i = 0; i < 8; ++i)
                #pragma unroll
                for (int j = 0; j < 8; ++j)
                    acc[i][j] = fmaf(av[i], bv[j], acc[i][j]);
        }
        __syncthreads();
    }
    const float* bp = bias + n0 + tx * 8;
    #pragma unroll
    for (int i = 0; i < 8; ++i) {
        int m = m0 + ty * 8 + i;
        ushort8_t o;
        #pragma unroll
        for (int j = 0; j < 8; ++j) o[j] = f2bf(acc[i][j] + bp[j]);
        *(ushort8_t*)(C + (size_t)m * H_DIM + n0 + tx * 8) = o;
    }
}

// ---------------- persistent cooperative decoder ----------------
struct Params {
    const float* encoded; const int* lens; const float* emb; const float* h0p;
    const int* texts; const int* text_lens;
    const float* w_score; const float* b_score;
    const float* b_ih0; const float* b_hh0; const float* b_ih1; const float* b_hh1;
    const ushort_t* ec; const ushort_t* encB;
    const ushort_t* Wrec; const ushort_t* Wih0; const ushort_t* Whh0;
    const ushort_t* Wih1; const ushort_t* Whh1;
    float* rec; float* context; float* denom;
    float* h0a; float* h0b; float* h1a; float* h1b;
    float* outputs; int* texts2; float* acc;
    int useEncB;
};

__global__ __launch_bounds__(NTHR, 4) void decoder_kernel(Params p) {
    cg::grid_group grid = cg::this_grid();
    const int tid = threadIdx.x;          // 0..1023
    const int bid = blockIdx.x;           // 0..255
    const int lane = tid & 63;
    const int wsub = tid >> 6;            // 0..15
    const int gid = bid * NTHR + tid;
    const int W = bid * 16 + wsub;        // 0..4095
    __shared__ float sctx[16][E_DIM];

    // ---- init ----
    if (gid < B_BATCH * L_STEPS) {
        int b = gid / L_STEPS, j = gid % L_STEPS;
        int v = (j < 100) ? p.texts[b * 100 + j] : 0;
        if (j == p.text_lens[b]) v = EOS_TOK;
        p.texts2[gid] = v;
    }
    if (gid < B_BATCH * H_DIM) {
        p.h0a[gid] = p.h0p[gid & (H_DIM - 1)];
        p.h1a[gid] = p.h0p[H_DIM + (gid & (H_DIM - 1))];
        p.context[gid & (B_BATCH * E_DIM - 1)] = 0.f;
    }
    if (gid < B_BATCH) p.denom[gid] = 0.f;
    if (gid < 2) p.acc[gid] = 0.f;
    grid.sync();

    // ---- initial rec from h0a: 4 h per wave ----
    {
        int b = W >> 7, hbase = (W & 127) * 4;
        const float* x = p.h0a + b * H_DIM + lane * 8;
        float x8[8];
        *(float4*)&x8[0] = *(const float4*)(x);
        *(float4*)&x8[4] = *(const float4*)(x + 4);
        #pragma unroll
        for (int i = 0; i < 4; ++i) {
            int h = hbase + i;
            ushort8_t w8 = *(const ushort8_t*)(p.Wrec + (size_t)h * H_DIM + lane * 8);
            float s = 0.f;
            #pragma unroll
            for (int j = 0; j < 8; ++j) s = fmaf(x8[j], bf2f(w8[j]), s);
            s = wave_sum(s);
            if (lane == 0) p.rec[b * H_DIM + h] = s;
        }
    }
    grid.sync();

    for (int l = 0; l < L_STEPS; ++l) {
        const float* h0cur = (l & 1) ? p.h0b : p.h0a;
        float*       h0nxt = (l & 1) ? p.h0a : p.h0b;
        const float* h1cur = (l & 1) ? p.h1b : p.h1a;
        float*       h1nxt = (l & 1) ? p.h1a : p.h1b;

        // ---- phase A: scores + exp + context partials + denom ----
        {
            int b = bid & 31;
            int chunk = (bid >> 5) * 16 + wsub;     // 0..127
            int len = p.lens[b];
            int t0 = chunk * ROWS_A;
            int t1 = min(t0 + ROWS_A, len);
            float rec8[8], w8[8];
            const float* rp = p.rec + b * H_DIM + lane * 8;
            *(float4*)&rec8[0] = *(const float4*)(rp);
            *(float4*)&rec8[4] = *(const float4*)(rp + 4);
            const float* wp = p.w_score + lane * 8;
            *(float4*)&w8[0] = *(const float4*)(wp);
            *(float4*)&w8[4] = *(const float4*)(wp + 4);
            float bsc = p.b_score[0];
            float acc8[8] = {0.f,0.f,0.f,0.f,0.f,0.f,0.f,0.f};
            float dsum = 0.f;
            if (p.useEncB) {
                for (int t = t0; t < t1; t += 2) {
                    int tb = (t + 1 < t1) ? (t + 1) : t;
                    size_t rowa = ((size_t)t  * B_BATCH + b) * H_DIM + lane * 8;
                    size_t rowb = ((size_t)tb * B_BATCH + b) * H_DIM + lane * 8;
                    ushort8_t e8a = *(const ushort8_t*)(p.ec + rowa);
                    ushort8_t e8b = *(const ushort8_t*)(p.ec + rowb);
                    ushort8_t v8a = *(const ushort8_t*)(p.encB + rowa);
                    ushort8_t v8b = *(const ushort8_t*)(p.encB + rowb);
                    float ss[2] = {0.f, 0.f};
                    #pragma unroll
                    for (int j = 0; j < 8; ++j) {
                        ss[0] = fmaf(tanh_f(bf2f(e8a[j]) + rec8[j]), w8[j], ss[0]);
                        ss[1] = fmaf(tanh_f(bf2f(e8b[j]) + rec8[j]), w8[j], ss[1]);
                    }
                    wave_sum_n<2>(ss);
                    float pv0 = __expf(ss[0] + bsc);
                    float pv1 = (tb != t) ? __expf(ss[1] + bsc) : 0.f;
                    dsum += pv0 + pv1;
                    #pragma unroll
                    for (int j = 0; j < 8; ++j)
                        acc8[j] += pv0 * bf2f(v8a[j]) + pv1 * bf2f(v8b[j]);
                }
            } else {
                for (int t = t0; t < t1; ++t) {
                    size_t row = ((size_t)t * B_BATCH + b) * H_DIM + lane * 8;
                    ushort8_t e8 = *(const ushort8_t*)(p.ec + row);
                    float s = 0.f;
                    #pragma unroll
                    for (int j = 0; j < 8; ++j)
                        s = fmaf(tanh_f(bf2f(e8[j]) + rec8[j]), w8[j], s);
                    s = wave_sum(s) + bsc;
                    float pv = __expf(s);
                    dsum += pv;
                    float v8[8];
                    const float* vp = p.encoded + row;
                    *(float4*)&v8[0] = *(const float4*)(vp);
                    *(float4*)&v8[4] = *(const float4*)(vp + 4);
                    #pragma unroll
                    for (int j = 0; j < 8; ++j)
                        acc8[j] = fmaf(pv, v8[j], acc8[j]);
                }
            }
            *(float4*)&sctx[wsub][lane * 8]     = *(float4*)&acc8[0];
            *(float4*)&sctx[wsub][lane * 8 + 4] = *(float4*)&acc8[4];
            __syncthreads();
            if (tid < E_DIM) {
                float csum = 0.f;
                #pragma unroll
                for (int w = 0; w < 16; ++w) csum += sctx[w][tid];
                if (csum != 0.f) atomicAdd(&p.context[b * E_DIM + tid], csum);
            }
            if (lane == 0 && dsum != 0.f) atomicAdd(&p.denom[b], dsum);
        }
        grid.sync();

        // ---- phase B: GRU layer 0 (4 h per wave) ----
        {
            int b = W >> 7, hbase = (W & 127) * 4;
            int token = (l > 0) ? p.texts2[b * L_STEPS + l - 1] : -1;
            float inv = __builtin_amdgcn_rcpf(p.denom[b]);
            float x16[16];
            int k0 = lane * 16;
            if (k0 < H_DIM) {
                if (token >= 0) {
                    const float* ep = p.emb + (size_t)token * H_DIM + k0;
                    #pragma unroll
                    for (int q = 0; q < 4; ++q)
                        *(float4*)&x16[q * 4] = *(const float4*)(ep + q * 4);
                } else {
                    #pragma unroll
                    for (int j = 0; j < 16; ++j) x16[j] = 0.f;
                }
            } else {
                const float* cp = p.context + b * E_DIM + (k0 - H_DIM);
                #pragma unroll
                for (int q = 0; q < 4; ++q) {
                    float4 c = *(const float4*)(cp + q * 4);
                    x16[q * 4 + 0] = c.x * inv; x16[q * 4 + 1] = c.y * inv;
                    x16[q * 4 + 2] = c.z * inv; x16[q * 4 + 3] = c.w * inv;
                }
            }
            float h8[8];
            const float* hp = h0cur + b * H_DIM + lane * 8;
            *(float4*)&h8[0] = *(const float4*)(hp);
            *(float4*)&h8[4] = *(const float4*)(hp + 4);
            const int IN = H_DIM + E_DIM;
            #pragma unroll
            for (int i = 0; i < 4; ++i) {
                int h = hbase + i;
                float v[6] = {0.f,0.f,0.f,0.f,0.f,0.f};
                #pragma unroll
                for (int g = 0; g < 3; ++g) {
                    const ushort_t* r = p.Wih0 + (size_t)(g * H_DIM + h) * IN + k0;
                    ushort8_t a = *(const ushort8_t*)(r);
                    ushort8_t c = *(const ushort8_t*)(r + 8);
                    #pragma unroll
                    for (int j = 0; j < 8; ++j) {
                        v[g] = fmaf(x16[j], bf2f(a[j]), v[g]);
                        v[g] = fmaf(x16[8 + j], bf2f(c[j]), v[g]);
                    }
                }
                #pragma unroll
                for (int g = 0; g < 3; ++g) {
                    const ushort_t* r = p.Whh0 + (size_t)(g * H_DIM + h) * H_DIM + lane * 8;
                    ushort8_t a = *(const ushort8_t*)(r);
                    #pragma unroll
                    for (int j = 0; j < 8; ++j)
                        v[3 + g] = fmaf(h8[j], bf2f(a[j]), v[3 + g]);
                }
                wave_sum_n<6>(v);
                if (lane == 0) {
                    float r = sigmoid_f(v[0] + p.b_ih0[h] + v[3] + p.b_hh0[h]);
                    float z = sigmoid_f(v[1] + p.b_ih0[H_DIM + h] + v[4] + p.b_hh0[H_DIM + h]);
                    float n = tanh_f(v[2] + p.b_ih0[2 * H_DIM + h] + r * (v[5] + p.b_hh0[2 * H_DIM + h]));
                    float hv = h0cur[b * H_DIM + h];
                    h0nxt[b * H_DIM + h] = (1.f - z) * n + z * hv;
                }
            }
        }
        grid.sync();

        // ---- phase C: GRU layer 1 + next rec + zero ctx/denom ----
        {
            if (gid < B_BATCH * E_DIM) p.context[gid] = 0.f;
            if (gid < B_BATCH) p.denom[gid] = 0.f;
            int b = W >> 7, hbase = (W & 127) * 4;
            float x8[8], g8[8];
            const float* xp = h0nxt + b * H_DIM + lane * 8;
            *(float4*)&x8[0] = *(const float4*)(xp);
            *(float4*)&x8[4] = *(const float4*)(xp + 4);
            const float* gp = h1cur + b * H_DIM + lane * 8;
            *(float4*)&g8[0] = *(const float4*)(gp);
            *(float4*)&g8[4] = *(const float4*)(gp + 4);
            #pragma unroll
            for (int i = 0; i < 4; ++i) {
                int h = hbase + i;
                float v[7] = {0.f,0.f,0.f,0.f,0.f,0.f,0.f};
                #pragma unroll
                for (int g = 0; g < 3; ++g) {
                    const ushort_t* r1 = p.Wih1 + (size_t)(g * H_DIM + h) * H_DIM + lane * 8;
                    ushort8_t a = *(const ushort8_t*)(r1);
                    const ushort_t* r2 = p.Whh1 + (size_t)(g * H_DIM + h) * H_DIM + lane * 8;
                    ushort8_t c = *(const ushort8_t*)(r2);
                    #pragma unroll
                    for (int j = 0; j < 8; ++j) {
                        v[g]     = fmaf(x8[j], bf2f(a[j]), v[g]);
                        v[3 + g] = fmaf(g8[j], bf2f(c[j]), v[3 + g]);
                    }
                }
                {
                    const ushort_t* r = p.Wrec + (size_t)h * H_DIM + lane * 8;
                    ushort8_t a = *(const ushort8_t*)(r);
                    #pragma unroll
                    for (int j = 0; j < 8; ++j)
                        v[6] = fmaf(x8[j], bf2f(a[j]), v[6]);
                }
                wave_sum_n<7>(v);
                if (lane == 0) {
                    float r = sigmoid_f(v[0] + p.b_ih1[h] + v[3] + p.b_hh1[h]);
                    float z = sigmoid_f(v[1] + p.b_ih1[H_DIM + h] + v[4] + p.b_hh1[H_DIM + h]);
                    float n = tanh_f(v[2] + p.b_ih1[2 * H_DIM + h] + r * (v[5] + p.b_hh1[2 * H_DIM + h]));
                    float hv = h1cur[b * H_DIM + h];
                    float out = (1.f - z) * n + z * hv;
                    h1nxt[b * H_DIM + h] = out;
                    p.outputs[((size_t)l * B_BATCH + b) * H_DIM + h] = out;
                    p.rec[b * H_DIM + h] = v[6];
                }
            }
        }
        grid.sync();
    }
}

// ---------------- loss ----------------
__global__ __launch_bounds__(256) void loss_kernel(
    const float* __restrict__ outputs, const int* __restrict__ texts2,
    const float* __restrict__ W_out, const float* __restrict__ b_out,
    float* __restrict__ acc)
{
    int wid = threadIdx.x >> 6, lane = threadIdx.x & 63;
    int gw = blockIdx.x * 4 + wid;
    int nw = gridDim.x * 4;
    float lsum = 0.f, lcnt = 0.f;
    for (int r = gw; r < B_BATCH * L_STEPS; r += nw) {
        int b = r / L_STEPS, l = r % L_STEPS;
        int label = texts2[r];
        const float* orow = outputs + ((size_t)l * B_BATCH + b) * H_DIM;
        int k = lane * 8;
        float o8[8];
        *(float4*)&o8[0] = *(const float4*)(orow + k);
        *(float4*)&o8[4] = *(const float4*)(orow + k + 4);
        float m = -1e30f, se = 0.f, ll = 0.f;
        for (int c = 0; c < NCLS; ++c) {
            const float* wrow = W_out + (size_t)c * H_DIM + k;
            float p = 0.f;
            #pragma unroll
            for (int j = 0; j < 8; ++j) p = fmaf(o8[j], wrow[j], p);
            float logit = wave_sum(p) + b_out[c];
            if (c == label) ll = logit;
            if (logit > m) { se = se * expf(m - logit) + 1.f; m = logit; }
            else           { se += expf(logit - m); }
        }
        float lse = m + logf(se);
        if (label != 0) { lsum += lse - ll; lcnt += 1.f; }
    }
    if (lane == 0) { atomicAdd(&acc[0], lsum); atomicAdd(&acc[1], lcnt); }
}

__global__ void finalize_kernel(const float* __restrict__ acc, float* __restrict__ out) {
    out[0] = acc[0] / fmaxf(acc[1], 1.0f);
}

// ---------------- launch ----------------
static inline size_t align256(size_t x) { return (x + 255) & ~(size_t)255; }

extern "C" void kernel_launch(void* const* d_in, const int* in_sizes, int n_in,
                              void* d_out, int out_size, void* d_ws, size_t ws_size,
                              hipStream_t stream) {
    (void)in_sizes; (void)n_in; (void)out_size;
    const float* encoded      = (const float*)d_in[0];
    const int*   encoded_lens = (const int*)d_in[1];
    const int*   texts        = (const int*)d_in[2];
    const int*   text_lens    = (const int*)d_in[3];
    const float* W_enc        = (const float*)d_in[4];
    const float* b_enc        = (const float*)d_in[5];
    const float* W_rec        = (const float*)d_in[6];
    const float* w_score      = (const float*)d_in[7];
    const float* b_score      = (const float*)d_in[8];
    const float* emb          = (const float*)d_in[9];
    const float* W_ih0        = (const float*)d_in[10];
    const float* W_hh0        = (const float*)d_in[11];
    const float* b_ih0        = (const float*)d_in[12];
    const float* b_hh0        = (const float*)d_in[13];
    const float* W_ih1        = (const float*)d_in[14];
    const float* W_hh1        = (const float*)d_in[15];
    const float* b_ih1        = (const float*)d_in[16];
    const float* b_hh1        = (const float*)d_in[17];
    const float* W_out        = (const float*)d_in[18];
    const float* b_out        = (const float*)d_in[19];
    const float* h0p          = (const float*)d_in[20];

    char* ws = (char*)d_ws;
    size_t off = 0;
    ushort_t* ec     = (ushort_t*)(ws + off); off = align256(off + (size_t)T_FRAMES * B_BATCH * H_DIM * 2);
    ushort_t* Wrecb  = (ushort_t*)(ws + off); off = align256(off + (size_t)H_DIM * H_DIM * 2);
    ushort_t* Wih0b  = (ushort_t*)(ws + off); off = align256(off + (size_t)3 * H_DIM * (H_DIM + E_DIM) * 2);
    ushort_t* Whh0b  = (ushort_t*)(ws + off); off = align256(off + (size_t)3 * H_DIM * H_DIM * 2);
    ushort_t* Wih1b  = (ushort_t*)(ws + off); off = align256(off + (size_t)3 * H_DIM * H_DIM * 2);
    ushort_t* Whh1b  = (ushort_t*)(ws + off); off = align256(off + (size_t)3 * H_DIM * H_DIM * 2);
    float* rec       = (float*)(ws + off); off = align256(off + (size_t)B_BATCH * H_DIM * 4);
    float* context   = (float*)(ws + off); off = align256(off + (size_t)B_BATCH * E_DIM * 4);
    float* denom     = (float*)(ws + off); off = align256(off + (size_t)B_BATCH * 4);
    float* h0a       = (float*)(ws + off); off = align256(off + (size_t)B_BATCH * H_DIM * 4);
    float* h0b       = (float*)(ws + off); off = align256(off + (size_t)B_BATCH * H_DIM * 4);
    float* h1a       = (float*)(ws + off); off = align256(off + (size_t)B_BATCH * H_DIM * 4);
    float* h1b       = (float*)(ws + off); off = align256(off + (size_t)B_BATCH * H_DIM * 4);
    float* outputs   = (float*)(ws + off); off = align256(off + (size_t)L_STEPS * B_BATCH * H_DIM * 4);
    int*   texts2    = (int*)(ws + off); off = align256(off + (size_t)B_BATCH * L_STEPS * 4);
    float* acc       = (float*)(ws + off); off = align256(off + 256);
    size_t encB_off  = off;
    size_t encB_bytes = (size_t)T_FRAMES * B_BATCH * E_DIM * 2;
    int useEncB = (encB_off + encB_bytes <= ws_size) ? 1 : 0;
    ushort_t* encB = (ushort_t*)(ws + encB_off);

    cvt_kernel<<<(H_DIM * H_DIM) / (256 * 8), 256, 0, stream>>>(W_rec, Wrecb, H_DIM * H_DIM);
    cvt_kernel<<<(3 * H_DIM * (H_DIM + E_DIM)) / (256 * 8), 256, 0, stream>>>(W_ih0, Wih0b, 3 * H_DIM * (H_DIM + E_DIM));
    cvt_kernel<<<(3 * H_DIM * H_DIM) / (256 * 8), 256, 0, stream>>>(W_hh0, Whh0b, 3 * H_DIM * H_DIM);
    cvt_kernel<<<(3 * H_DIM * H_DIM) / (256 * 8), 256, 0, stream>>>(W_ih1, Wih1b, 3 * H_DIM * H_DIM);
    cvt_kernel<<<(3 * H_DIM * H_DIM) / (256 * 8), 256, 0, stream>>>(W_hh1, Whh1b, 3 * H_DIM * H_DIM);
    if (useEncB) {
        cvt_kernel<<<(T_FRAMES * B_BATCH * E_DIM) / (256 * 8), 256, 0, stream>>>(
            encoded, encB, T_FRAMES * B_BATCH * E_DIM);
    }
    enc_gemm_kernel<<<dim3(H_DIM / GTN, (T_FRAMES * B_BATCH) / GTM), 256, 0, stream>>>(
        encoded, W_enc, b_enc, ec);

    Params prm;
    prm.encoded = encoded; prm.lens = encoded_lens; prm.emb = emb; prm.h0p = h0p;
    prm.texts = texts; prm.text_lens = text_lens;
    prm.w_score = w_score; prm.b_score = b_score;
    prm.b_ih0 = b_ih0; prm.b_hh0 = b_hh0; prm.b_ih1 = b_ih1; prm.b_hh1 = b_hh1;
    prm.ec = ec; prm.encB = encB;
    prm.Wrec = Wrecb; prm.Wih0 = Wih0b; prm.Whh0 = Whh0b; prm.Wih1 = Wih1b; prm.Whh1 = Whh1b;
    prm.rec = rec; prm.context = context; prm.denom = denom;
    prm.h0a = h0a; prm.h0b = h0b; prm.h1a = h1a; prm.h1b = h1b;
    prm.outputs = outputs; prm.texts2 = texts2; prm.acc = acc;
    prm.useEncB = useEncB;

    void* args[] = { &prm };
    hipLaunchCooperativeKernel((const void*)decoder_kernel, dim3(NBLK), dim3(NTHR),
                               args, 0, stream);

    loss_kernel<<<64, 256, 0, stream>>>(outputs, texts2, W_out, b_out, acc);
    finalize_kernel<<<1, 1, 0, stream>>>(acc, (float*)d_out);
}